// Round 10
// baseline (119.829 us; speedup 1.0000x reference)
//
#include <hip/hip_runtime.h>
#include <math.h>

#define B    64
#define CTRL 512
#define KEY  64
#define MEMU 16384

__device__ __forceinline__ float softplusf(float x) {
    return x > 20.f ? x : log1pf(expf(x));
}

// ---------------- K2: fused head-scalar prologue + content scores ----------
// Prologue: each of the 16 blocks per batch redundantly computes the 70-row
// linear head (k, beta, g, s, y) from L2/L3-hot weights (~140 MACs/thread).
// Streaming body: PROVEN row-per-thread pattern (R0-R2). Do NOT interleave
// multiple row-streams per lane (R5); do NOT shuffle-reduce per row (R3).
__global__ __launch_bounds__(256) void k2_scores(
    const float* __restrict__ cs,
    const float* __restrict__ key_W, const float* __restrict__ key_b,
    const float* __restrict__ ks_W,  const float* __restrict__ ks_b,
    const float* __restrict__ ig_W,  const float* __restrict__ ig_b,
    const float* __restrict__ sw_W,  const float* __restrict__ sw_b,
    const float* __restrict__ sf_W,  const float* __restrict__ sf_b,
    const float* __restrict__ mem,
    float* __restrict__ ws_scal, float* __restrict__ ws_e, float* __restrict__ ws_pe)
{
    const int b = blockIdx.y;
    const int chunk = blockIdx.x;          // 0..15, 1024 rows each
    const int t = threadIdx.x, wv = t >> 6, lane = t & 63;
    __shared__ float cs_s[CTRL];
    __shared__ float k_s[KEY];
    __shared__ float h_s[8];
    __shared__ float sc_s[8];
    __shared__ float red[4];

    for (int i = t; i < CTRL; i += 256) cs_s[i] = cs[b * CTRL + i];
    __syncthreads();

    // 70 rows of the linear head: wave wv handles rows o ≡ wv (mod 4)
    for (int o = wv; o < 70; o += 4) {
        const float* W; float bias;
        if (o < 64)       { W = key_W + o * CTRL;       bias = key_b[o]; }
        else if (o == 64) { W = ks_W;                   bias = ks_b[0]; }
        else if (o == 65) { W = ig_W;                   bias = ig_b[0]; }
        else if (o < 69)  { W = sw_W + (o - 66) * CTRL; bias = sw_b[o - 66]; }
        else              { W = sf_W;                   bias = sf_b[0]; }
        float d = 0.f;
        for (int j = lane; j < CTRL; j += 64) d += cs_s[j] * W[j];
        #pragma unroll
        for (int off = 32; off >= 1; off >>= 1) d += __shfl_xor(d, off, 64);
        if (lane == 0) {
            float r = d + bias;
            if (o < 64) k_s[o] = r;
            else        h_s[o - 64] = r;
        }
    }
    __syncthreads();
    if (wv == 0) {
        float kv = k_s[lane];
        float sq = kv * kv;
        #pragma unroll
        for (int off = 32; off >= 1; off >>= 1) sq += __shfl_xor(sq, off, 64);
        if (lane == 0) {
            float knorm = sqrtf(sq);
            float beta = softplusf(h_s[0]);
            float g    = 1.f / (1.f + expf(-h_s[1]));
            float m3   = fmaxf(fmaxf(h_s[2], h_s[3]), h_s[4]);
            float e0 = expf(h_s[2] - m3), e1 = expf(h_s[3] - m3), e2 = expf(h_s[4] - m3);
            float inv3 = 1.f / (e0 + e1 + e2);
            float y = 1.f + softplusf(h_s[5]);
            sc_s[0] = beta; sc_s[1] = g;
            sc_s[2] = e0 * inv3; sc_s[3] = e1 * inv3; sc_s[4] = e2 * inv3;
            sc_s[5] = y; sc_s[6] = knorm;
            if (chunk == 0) {   // publish for kC (kernel boundary orders it)
                float* sc = ws_scal + b * 8;
                #pragma unroll
                for (int q = 0; q < 7; ++q) sc[q] = sc_s[q];
            }
        }
    }
    __syncthreads();

    const float beta  = sc_s[0];
    const float knorm = sc_s[6];
    float kk[KEY];
    #pragma unroll
    for (int j = 0; j < KEY; ++j) kk[j] = k_s[j];

    float esum = 0.f;
    #pragma unroll
    for (int i = 0; i < 4; ++i) {
        const int m = chunk * 1024 + i * 256 + t;
        const float4* rp = (const float4*)(mem + ((size_t)b * MEMU + m) * KEY);
        float dot = 0.f, sq = 0.f;
        #pragma unroll
        for (int q = 0; q < 16; ++q) {
            float4 v = rp[q];
            dot += v.x * kk[4*q+0] + v.y * kk[4*q+1] + v.z * kk[4*q+2] + v.w * kk[4*q+3];
            sq  += v.x * v.x + v.y * v.y + v.z * v.z + v.w * v.w;
        }
        const float denom = fmaxf(sqrtf(sq) * knorm, 1e-8f);
        const float e = expf(beta * (dot / denom) - beta);
        ws_e[b * MEMU + m] = e;
        esum += e;
    }
    #pragma unroll
    for (int off = 32; off >= 1; off >>= 1) esum += __shfl_xor(esum, off, 64);
    if (lane == 0) red[wv] = esum;
    __syncthreads();
    if (t == 0) ws_pe[b * 16 + chunk] = red[0] + red[1] + red[2] + red[3];
}

// ---------------- KC: fused interpolate+shift+sharpen + w-out + data -------
// Computes sharp per element directly from e/pw (3-tap), writes UNNORMALIZED
// sharp to out_w (kD rescales), accumulates unnormalized data partials.
// Normalization deferred: data = (sum sharp*mem)/S, w = sharp/S.
__global__ __launch_bounds__(256) void kC_data(
    const float* __restrict__ mem, const float* __restrict__ pw,
    const float* __restrict__ ws_e, const float* __restrict__ ws_pe,
    const float* __restrict__ ws_scal,
    float* __restrict__ out_w, float* __restrict__ ws_pd,
    float* __restrict__ ws_ps)
{
    const int b     = (B - 1) - blockIdx.y;      // reverse order (free L3 residue)
    const int chunk = 63 - blockIdx.x;
    const int t = threadIdx.x, wv = t >> 6, lane = t & 63;
    __shared__ float w_lds[256];
    __shared__ float red[4][64];
    __shared__ float red1[4];

    float sum_e = 0.f;
    #pragma unroll
    for (int i = 0; i < 16; ++i) sum_e += ws_pe[b * 16 + i];
    const float inv_e = 1.f / sum_e;
    const float g  = ws_scal[b*8+1];
    const float s0 = ws_scal[b*8+2], s1 = ws_scal[b*8+3], s2 = ws_scal[b*8+4];
    const float y  = ws_scal[b*8+5];
    const float cg = 1.f - g;

    const int m0 = chunk * 256;
    const int m  = m0 + t;
    const int mm = (m + MEMU - 1) & (MEMU - 1);
    const int mp = (m + 1) & (MEMU - 1);
    const float* eb = ws_e + b * MEMU;
    const float* pb = pw   + b * MEMU;
    const float wim = g * eb[mm] * inv_e + cg * pb[mm];
    const float wi0 = g * eb[m ] * inv_e + cg * pb[m ];
    const float wip = g * eb[mp] * inv_e + cg * pb[mp];
    const float sh  = s0 * wim + s1 * wi0 + s2 * wip;
    const float sp  = expf(y * logf(sh));    // sh > 0 always
    out_w[b * MEMU + m] = sp;                // unnormalized; kD rescales
    w_lds[t] = sp;

    // per-chunk sharp-sum partial
    float ssum = sp;
    #pragma unroll
    for (int off = 32; off >= 1; off >>= 1) ssum += __shfl_xor(ssum, off, 64);
    if (lane == 0) red1[wv] = ssum;
    __syncthreads();
    if (t == 0) ws_ps[b * 64 + chunk] = red1[0] + red1[1] + red1[2] + red1[3];

    // streaming accumulate: wave wv covers rows [wv*64, wv*64+64), 4 rows/step
    const float* mb = mem + ((size_t)b * MEMU + m0 + wv * 64) * KEY;
    const int rsub = lane >> 4;
    const int c4   = (lane & 15) * 4;
    float4 acc = make_float4(0.f, 0.f, 0.f, 0.f);
    #pragma unroll
    for (int s = 0; s < 16; ++s) {
        const int r = s * 4 + rsub;
        const float4 v = *(const float4*)(mb + (size_t)r * KEY + c4);
        const float wr = w_lds[wv * 64 + r];
        acc.x += wr * v.x; acc.y += wr * v.y; acc.z += wr * v.z; acc.w += wr * v.w;
    }
    #pragma unroll
    for (int off = 16; off <= 32; off <<= 1) {
        acc.x += __shfl_xor(acc.x, off, 64);
        acc.y += __shfl_xor(acc.y, off, 64);
        acc.z += __shfl_xor(acc.z, off, 64);
        acc.w += __shfl_xor(acc.w, off, 64);
    }
    if (lane < 16) {
        red[wv][c4 + 0] = acc.x; red[wv][c4 + 1] = acc.y;
        red[wv][c4 + 2] = acc.z; red[wv][c4 + 3] = acc.w;
    }
    __syncthreads();
    if (t < 64) {
        ws_pd[(b * 64 + chunk) * 64 + t] =
            red[0][t] + red[1][t] + red[2][t] + red[3][t];
    }
}

// ---------------- KD: final rescale — data reduce + w normalize ------------
// blocks 0..63: data[b] = (sum of partials)/S_b.  blocks 64..575: w *= 1/S_b.
__global__ __launch_bounds__(256) void kD_final(
    const float* __restrict__ ws_pd, const float* __restrict__ ws_ps,
    float* __restrict__ out)
{
    const int bid = blockIdx.x, t = threadIdx.x;
    if (bid < B) {
        const int b = bid;
        float S = 0.f;
        #pragma unroll
        for (int c = 0; c < 64; ++c) S += ws_ps[b * 64 + c];
        const float inv = 1.f / (S + 1e-16f);
        const int j = t & 63, g4 = t >> 6;
        const float* pd = ws_pd + b * 4096;
        float s = 0.f;
        #pragma unroll
        for (int c = g4; c < 64; c += 4) s += pd[c * 64 + j];
        __shared__ float red[4][64];
        red[g4][j] = s;
        __syncthreads();
        if (t < 64)
            out[(size_t)B * MEMU + b * KEY + t] =
                (red[0][t] + red[1][t] + red[2][t] + red[3][t]) * inv;
    } else {
        const int u = bid - B;          // 0..511: 8 segments x 64 batches
        const int b = u >> 3, seg = u & 7;
        float S = 0.f;
        #pragma unroll
        for (int c = 0; c < 64; ++c) S += ws_ps[b * 64 + c];
        const float inv = 1.f / (S + 1e-16f);
        float* wbase = out + (size_t)b * MEMU + seg * 2048 + t * 8;
        float4 a0 = *(float4*)wbase;
        float4 a1 = *(float4*)(wbase + 4);
        a0.x *= inv; a0.y *= inv; a0.z *= inv; a0.w *= inv;
        a1.x *= inv; a1.y *= inv; a1.z *= inv; a1.w *= inv;
        *(float4*)wbase       = a0;
        *(float4*)(wbase + 4) = a1;
    }
}

extern "C" void kernel_launch(void* const* d_in, const int* in_sizes, int n_in,
                              void* d_out, int out_size, void* d_ws, size_t ws_size,
                              hipStream_t stream) {
    (void)in_sizes; (void)n_in; (void)out_size; (void)ws_size;
    const float* cs    = (const float*)d_in[0];
    const float* pw    = (const float*)d_in[1];
    const float* mem   = (const float*)d_in[2];
    const float* key_W = (const float*)d_in[3];
    const float* key_b = (const float*)d_in[4];
    const float* ks_W  = (const float*)d_in[5];
    const float* ks_b  = (const float*)d_in[6];
    const float* ig_W  = (const float*)d_in[7];
    const float* ig_b  = (const float*)d_in[8];
    const float* sw_W  = (const float*)d_in[9];
    const float* sw_b  = (const float*)d_in[10];
    const float* sf_W  = (const float*)d_in[11];
    const float* sf_b  = (const float*)d_in[12];
    float* out = (float*)d_out;
    float* ws  = (float*)d_ws;

    // workspace layout (floats)
    float* ws_scal = ws;                          // 64*8
    float* ws_e    = ws_scal + B * 8;             // 64*16384
    float* ws_pe   = ws_e + (size_t)B * MEMU;     // 64*16
    float* ws_ps   = ws_pe + B * 16;              // 64*64
    float* ws_pd   = ws_ps + B * 64;              // 64*64*64

    k2_scores<<<dim3(16, B), dim3(256), 0, stream>>>(cs, key_W, key_b, ks_W, ks_b,
                                                     ig_W, ig_b, sw_W, sw_b, sf_W, sf_b,
                                                     mem, ws_scal, ws_e, ws_pe);
    kC_data<<<dim3(64, B), dim3(256), 0, stream>>>(mem, pw, ws_e, ws_pe, ws_scal,
                                                   out, ws_pd, ws_ps);
    kD_final<<<dim3(B + 512), dim3(256), 0, stream>>>(ws_pd, ws_ps, out);
}

// Round 11
// 117.068 us; speedup vs baseline: 1.0236x; 1.0236x over previous
//
#include <hip/hip_runtime.h>
#include <math.h>

#define B    64
#define CTRL 512
#define KEY  64
#define MEMU 16384

__device__ __forceinline__ float softplusf(float x) {
    return x > 20.f ? x : log1pf(expf(x));
}

// ---------------- K1: per-batch head scalars -----------------------------
__global__ __launch_bounds__(256) void k1_scalars(
    const float* __restrict__ cs,
    const float* __restrict__ key_W, const float* __restrict__ key_b,
    const float* __restrict__ ks_W,  const float* __restrict__ ks_b,
    const float* __restrict__ ig_W,  const float* __restrict__ ig_b,
    const float* __restrict__ sw_W,  const float* __restrict__ sw_b,
    const float* __restrict__ sf_W,  const float* __restrict__ sf_b,
    float* __restrict__ ws_k, float* __restrict__ ws_scal)
{
    __shared__ float cs_s[CTRL];
    __shared__ float k_s[KEY];
    __shared__ float h_s[8];
    const int b = blockIdx.x;
    const int t = threadIdx.x;
    for (int i = t; i < CTRL; i += 256) cs_s[i] = cs[b * CTRL + i];
    __syncthreads();
    const int wave = t >> 6, lane = t & 63;
    for (int o = wave; o < 70; o += 4) {
        const float* W; float bias;
        if (o < 64)       { W = key_W + o * CTRL;      bias = key_b[o]; }
        else if (o == 64) { W = ks_W;                  bias = ks_b[0]; }
        else if (o == 65) { W = ig_W;                  bias = ig_b[0]; }
        else if (o < 69)  { W = sw_W + (o - 66) * CTRL; bias = sw_b[o - 66]; }
        else              { W = sf_W;                  bias = sf_b[0]; }
        float d = 0.f;
        for (int j = lane; j < CTRL; j += 64) d += cs_s[j] * W[j];
        #pragma unroll
        for (int off = 32; off >= 1; off >>= 1) d += __shfl_xor(d, off, 64);
        if (lane == 0) {
            float r = d + bias;
            if (o < 64) { k_s[o] = r; ws_k[b * KEY + o] = r; }
            else        h_s[o - 64] = r;
        }
    }
    __syncthreads();
    if (wave == 0) {
        float kv = k_s[lane];
        float sq = kv * kv;
        #pragma unroll
        for (int off = 32; off >= 1; off >>= 1) sq += __shfl_xor(sq, off, 64);
        if (lane == 0) {
            float knorm = sqrtf(sq);
            float beta = softplusf(h_s[0]);
            float g    = 1.f / (1.f + expf(-h_s[1]));
            float m3   = fmaxf(fmaxf(h_s[2], h_s[3]), h_s[4]);
            float e0 = expf(h_s[2] - m3), e1 = expf(h_s[3] - m3), e2 = expf(h_s[4] - m3);
            float inv3 = 1.f / (e0 + e1 + e2);
            float y = 1.f + softplusf(h_s[5]);
            float* sc = ws_scal + b * 8;
            sc[0] = beta; sc[1] = g;
            sc[2] = e0 * inv3; sc[3] = e1 * inv3; sc[4] = e2 * inv3;
            sc[5] = y; sc[6] = knorm;
        }
    }
}

// ---------------- K2: big pass 1 over memory (row-per-thread, sequential) --
// PROVEN pattern (R0-R2): each thread fully consumes one 256B row per i-step.
// Do NOT interleave multiple row-streams per lane (R5); do NOT shuffle-reduce
// per row (R3); do NOT fuse the k1 prologue in redundantly (R9: 16x redundancy
// costs what the saved dispatch gains).
__global__ __launch_bounds__(256) void k2_scores(
    const float* __restrict__ mem,
    const float* __restrict__ ws_k, const float* __restrict__ ws_scal,
    float* __restrict__ ws_e, float* __restrict__ ws_pe)
{
    const int b = blockIdx.y;
    const int chunk = blockIdx.x;          // 0..15, 1024 rows each
    const int t = threadIdx.x;
    const float beta  = ws_scal[b * 8 + 0];
    const float knorm = ws_scal[b * 8 + 6];
    float kk[KEY];
    #pragma unroll
    for (int j = 0; j < KEY; ++j) kk[j] = ws_k[b * KEY + j];

    float esum = 0.f;
    #pragma unroll
    for (int i = 0; i < 4; ++i) {
        const int m = chunk * 1024 + i * 256 + t;
        const float4* rp = (const float4*)(mem + ((size_t)b * MEMU + m) * KEY);
        float dot = 0.f, sq = 0.f;
        #pragma unroll
        for (int q = 0; q < 16; ++q) {
            float4 v = rp[q];
            dot += v.x * kk[4*q+0] + v.y * kk[4*q+1] + v.z * kk[4*q+2] + v.w * kk[4*q+3];
            sq  += v.x * v.x + v.y * v.y + v.z * v.z + v.w * v.w;
        }
        const float denom = fmaxf(sqrtf(sq) * knorm, 1e-8f);
        const float e = expf(beta * (dot / denom) - beta);
        ws_e[b * MEMU + m] = e;
        esum += e;
    }
    __shared__ float red[4];
    #pragma unroll
    for (int off = 32; off >= 1; off >>= 1) esum += __shfl_xor(esum, off, 64);
    if ((t & 63) == 0) red[t >> 6] = esum;
    __syncthreads();
    if (t == 0) ws_pe[b * 16 + chunk] = red[0] + red[1] + red[2] + red[3];
}

// ---------------- KC: fused interpolate+shift+sharpen + w-out + data -------
// Computes sharp per element directly from e/pw (3-tap), writes UNNORMALIZED
// sharp to out_w (kD rescales), accumulates unnormalized data partials.
// Normalization deferred: data = (sum sharp*mem)/S, w = sharp/S.
__global__ __launch_bounds__(256) void kC_data(
    const float* __restrict__ mem, const float* __restrict__ pw,
    const float* __restrict__ ws_e, const float* __restrict__ ws_pe,
    const float* __restrict__ ws_scal,
    float* __restrict__ out_w, float* __restrict__ ws_pd,
    float* __restrict__ ws_ps)
{
    const int b     = (B - 1) - blockIdx.y;      // reverse order (free L3 residue)
    const int chunk = 63 - blockIdx.x;
    const int t = threadIdx.x, wv = t >> 6, lane = t & 63;
    __shared__ float w_lds[256];
    __shared__ float red[4][64];
    __shared__ float red1[4];

    float sum_e = 0.f;
    #pragma unroll
    for (int i = 0; i < 16; ++i) sum_e += ws_pe[b * 16 + i];
    const float inv_e = 1.f / sum_e;
    const float g  = ws_scal[b*8+1];
    const float s0 = ws_scal[b*8+2], s1 = ws_scal[b*8+3], s2 = ws_scal[b*8+4];
    const float y  = ws_scal[b*8+5];
    const float cg = 1.f - g;

    const int m0 = chunk * 256;
    const int m  = m0 + t;
    const int mm = (m + MEMU - 1) & (MEMU - 1);
    const int mp = (m + 1) & (MEMU - 1);
    const float* eb = ws_e + b * MEMU;
    const float* pb = pw   + b * MEMU;
    const float wim = g * eb[mm] * inv_e + cg * pb[mm];
    const float wi0 = g * eb[m ] * inv_e + cg * pb[m ];
    const float wip = g * eb[mp] * inv_e + cg * pb[mp];
    const float sh  = s0 * wim + s1 * wi0 + s2 * wip;
    const float sp  = expf(y * logf(sh));    // sh > 0 always
    out_w[b * MEMU + m] = sp;                // unnormalized; kD rescales (L2-hot reread)
    w_lds[t] = sp;

    // per-chunk sharp-sum partial
    float ssum = sp;
    #pragma unroll
    for (int off = 32; off >= 1; off >>= 1) ssum += __shfl_xor(ssum, off, 64);
    if (lane == 0) red1[wv] = ssum;
    __syncthreads();
    if (t == 0) ws_ps[b * 64 + chunk] = red1[0] + red1[1] + red1[2] + red1[3];

    // streaming accumulate: wave wv covers rows [wv*64, wv*64+64), 4 rows/step
    const float* mb = mem + ((size_t)b * MEMU + m0 + wv * 64) * KEY;
    const int rsub = lane >> 4;
    const int c4   = (lane & 15) * 4;
    float4 acc = make_float4(0.f, 0.f, 0.f, 0.f);
    #pragma unroll
    for (int s = 0; s < 16; ++s) {
        const int r = s * 4 + rsub;
        const float4 v = *(const float4*)(mb + (size_t)r * KEY + c4);
        const float wr = w_lds[wv * 64 + r];
        acc.x += wr * v.x; acc.y += wr * v.y; acc.z += wr * v.z; acc.w += wr * v.w;
    }
    #pragma unroll
    for (int off = 16; off <= 32; off <<= 1) {
        acc.x += __shfl_xor(acc.x, off, 64);
        acc.y += __shfl_xor(acc.y, off, 64);
        acc.z += __shfl_xor(acc.z, off, 64);
        acc.w += __shfl_xor(acc.w, off, 64);
    }
    if (lane < 16) {
        red[wv][c4 + 0] = acc.x; red[wv][c4 + 1] = acc.y;
        red[wv][c4 + 2] = acc.z; red[wv][c4 + 3] = acc.w;
    }
    __syncthreads();
    if (t < 64) {
        ws_pd[(b * 64 + chunk) * 64 + t] =
            red[0][t] + red[1][t] + red[2][t] + red[3][t];
    }
}

// ---------------- KD: final rescale — data reduce + w normalize ------------
// blocks 0..63: data[b] = (sum of partials)/S_b.  blocks 64..575: w *= 1/S_b.
__global__ __launch_bounds__(256) void kD_final(
    const float* __restrict__ ws_pd, const float* __restrict__ ws_ps,
    float* __restrict__ out)
{
    const int bid = blockIdx.x, t = threadIdx.x;
    if (bid < B) {
        const int b = bid;
        float S = 0.f;
        #pragma unroll
        for (int c = 0; c < 64; ++c) S += ws_ps[b * 64 + c];
        const float inv = 1.f / (S + 1e-16f);
        const int j = t & 63, g4 = t >> 6;
        const float* pd = ws_pd + b * 4096;
        float s = 0.f;
        #pragma unroll
        for (int c = g4; c < 64; c += 4) s += pd[c * 64 + j];
        __shared__ float red[4][64];
        red[g4][j] = s;
        __syncthreads();
        if (t < 64)
            __builtin_nontemporal_store(
                (red[0][t] + red[1][t] + red[2][t] + red[3][t]) * inv,
                &out[(size_t)B * MEMU + b * KEY + t]);
    } else {
        const int u = bid - B;          // 0..511: 8 segments x 64 batches
        const int b = u >> 3, seg = u & 7;
        float S = 0.f;
        #pragma unroll
        for (int c = 0; c < 64; ++c) S += ws_ps[b * 64 + c];
        const float inv = 1.f / (S + 1e-16f);
        float* wbase = out + (size_t)b * MEMU + seg * 2048 + t * 8;
        float4 a0 = *(float4*)wbase;       // L2-hot (just written by kC)
        float4 a1 = *(float4*)(wbase + 4);
        a0.x *= inv; a0.y *= inv; a0.z *= inv; a0.w *= inv;
        a1.x *= inv; a1.y *= inv; a1.z *= inv; a1.w *= inv;
        __builtin_nontemporal_store(a0.x, wbase + 0);
        __builtin_nontemporal_store(a0.y, wbase + 1);
        __builtin_nontemporal_store(a0.z, wbase + 2);
        __builtin_nontemporal_store(a0.w, wbase + 3);
        __builtin_nontemporal_store(a1.x, wbase + 4);
        __builtin_nontemporal_store(a1.y, wbase + 5);
        __builtin_nontemporal_store(a1.z, wbase + 6);
        __builtin_nontemporal_store(a1.w, wbase + 7);
    }
}

extern "C" void kernel_launch(void* const* d_in, const int* in_sizes, int n_in,
                              void* d_out, int out_size, void* d_ws, size_t ws_size,
                              hipStream_t stream) {
    (void)in_sizes; (void)n_in; (void)out_size; (void)ws_size;
    const float* cs    = (const float*)d_in[0];
    const float* pw    = (const float*)d_in[1];
    const float* mem   = (const float*)d_in[2];
    const float* key_W = (const float*)d_in[3];
    const float* key_b = (const float*)d_in[4];
    const float* ks_W  = (const float*)d_in[5];
    const float* ks_b  = (const float*)d_in[6];
    const float* ig_W  = (const float*)d_in[7];
    const float* ig_b  = (const float*)d_in[8];
    const float* sw_W  = (const float*)d_in[9];
    const float* sw_b  = (const float*)d_in[10];
    const float* sf_W  = (const float*)d_in[11];
    const float* sf_b  = (const float*)d_in[12];
    float* out = (float*)d_out;
    float* ws  = (float*)d_ws;

    // workspace layout (floats)
    float* ws_k    = ws;                          // 64*64
    float* ws_scal = ws_k + B * KEY;              // 64*8
    float* ws_e    = ws_scal + B * 8;             // 64*16384
    float* ws_pe   = ws_e + (size_t)B * MEMU;     // 64*16
    float* ws_ps   = ws_pe + B * 16;              // 64*64
    float* ws_pd   = ws_ps + B * 64;              // 64*64*64

    k1_scalars<<<dim3(B), dim3(256), 0, stream>>>(cs, key_W, key_b, ks_W, ks_b,
                                                  ig_W, ig_b, sw_W, sw_b, sf_W, sf_b,
                                                  ws_k, ws_scal);
    k2_scores<<<dim3(16, B), dim3(256), 0, stream>>>(mem, ws_k, ws_scal, ws_e, ws_pe);
    kC_data<<<dim3(64, B), dim3(256), 0, stream>>>(mem, pw, ws_e, ws_pe, ws_scal,
                                                   out, ws_pd, ws_ps);
    kD_final<<<dim3(B + 512), dim3(256), 0, stream>>>(ws_pd, ws_ps, out);
}